// Round 1
// 5708.014 us; speedup vs baseline: 1.1184x; 1.1184x over previous
//
#include <hip/hip_runtime.h>
#include <hip/hip_bf16.h>
#include <stdint.h>

#define B_ 64
#define S_ 512
#define I_ 512
#define H_ 1024
#define NB 64          // blocks; block g owns 16 h-columns [16g, 16g+16)
#define HWORDS (B_ * H_)   // 65536 words per h buffer

typedef __attribute__((ext_vector_type(8))) __bf16 bf16x8;
typedef __attribute__((ext_vector_type(4))) float f32x4;
typedef __attribute__((ext_vector_type(4))) unsigned u32x4;

__device__ __forceinline__ unsigned short f2bf(float f) {
    unsigned u = __float_as_uint(f);
    u += 0x7FFFu + ((u >> 16) & 1u);   // RNE
    return (unsigned short)(u >> 16);
}

__device__ __forceinline__ bf16x8 ld8(const unsigned short* p) {
    return *(const bf16x8*)p;
}

// 16B load that bypasses L1+L2 (reads at the device coherence point). Data is
// NOT valid until a following s_waitcnt vmcnt(0) (+ sched_barrier, rule #18).
__device__ __forceinline__ void ld16_cv(u32x4& d, const unsigned* p) {
    asm volatile("global_load_dwordx4 %0, %1, off sc0 sc1" : "=v"(d) : "v"(p));
}

// ---------- prep: convert x to bf16 ----------
__global__ __launch_bounds__(256) void gru_prep(const float* __restrict__ x,
                                                unsigned short* __restrict__ xbf) {
    const int NX = (B_ * S_ * I_) / 4;
    int stride = gridDim.x * blockDim.x;
    for (int i = blockIdx.x * blockDim.x + threadIdx.x; i < NX; i += stride) {
        float4 v = ((const float4*)x)[i];
        ushort4 o;
        o.x = f2bf(v.x); o.y = f2bf(v.y); o.z = f2bf(v.z); o.w = f2bf(v.w);
        ((ushort4*)xbf)[i] = o;
    }
}

// ---------- tagged-exchange helpers ----------
// h is exchanged as 4B words: (step_tag<<16) | bf16(h). The tag makes every
// word self-validating, so the load IS the poll: no flags, no producer drain,
// no block barriers in the main loop. Group = 8 K-chunks (ki) = 16 dwordx4.
template<int G4>
__device__ __forceinline__ void issue_group(u32x4* d, const unsigned* hb) {
    const unsigned* p = hb + G4 * 256;
    #pragma unroll
    for (int kk = 0; kk < 8; ++kk) {
        ld16_cv(d[2 * kk],     p + kk * 32);
        ld16_cv(d[2 * kk + 1], p + kk * 32 + 4);
    }
    __builtin_amdgcn_sched_barrier(0);   // keep issues ahead of following MFMAs
}

__device__ __forceinline__ unsigned badof(const u32x4& v, unsigned tt) {
    return (v.x ^ tt) | (v.y ^ tt) | (v.z ^ tt) | (v.w ^ tt);
}

template<int G4>
__device__ __forceinline__ void wait_group(u32x4* d, const unsigned* hb, unsigned tt) {
    asm volatile("s_waitcnt vmcnt(0)" ::: "memory");
    __builtin_amdgcn_sched_barrier(0);   // rule #18: block hoisting past the wait
    int tries = 0;
    for (;;) {
        unsigned bad = 0;
        #pragma unroll
        for (int j = 0; j < 16; ++j) bad |= badof(d[j], tt);
        if (!__any((int)(bad >> 16))) return;      // all 256 tags == t
        if (++tries > 200000) return;              // fail loud, don't hang
        __builtin_amdgcn_s_sleep(2);               // throttle mall hammering
        issue_group<G4>(d, hb);
        asm volatile("s_waitcnt vmcnt(0)" ::: "memory");
        __builtin_amdgcn_sched_barrier(0);
    }
}

template<int G4>
__device__ __forceinline__ void mfma_group(const u32x4* d,
        const unsigned short* wr, const unsigned short* wz, const unsigned short* wn,
        f32x4& ar, f32x4& az, f32x4& ahn) {
    #pragma unroll
    for (int kk = 0; kk < 8; ++kk) {
        const int ki = G4 * 8 + kk;
        u32x4 lo = d[2 * kk], hi = d[2 * kk + 1];
        union { unsigned u[4]; bf16x8 v; } a;
        // strip tags: pack low16 of word pairs -> bf16x8 in memory order
        a.u[0] = __builtin_amdgcn_perm(lo.y, lo.x, 0x05040100u);
        a.u[1] = __builtin_amdgcn_perm(lo.w, lo.z, 0x05040100u);
        a.u[2] = __builtin_amdgcn_perm(hi.y, hi.x, 0x05040100u);
        a.u[3] = __builtin_amdgcn_perm(hi.w, hi.z, 0x05040100u);
        bf16x8 br = *(const bf16x8*)&wr[ki * 32];
        bf16x8 bz = *(const bf16x8*)&wz[ki * 32];
        bf16x8 bn = *(const bf16x8*)&wn[ki * 32];
        ar  = __builtin_amdgcn_mfma_f32_16x16x32_bf16(a.v, br, ar, 0, 0, 0);
        az  = __builtin_amdgcn_mfma_f32_16x16x32_bf16(a.v, bz, az, 0, 0, 0);
        ahn = __builtin_amdgcn_mfma_f32_16x16x32_bf16(a.v, bn, ahn, 0, 0, 0);
    }
}

// ---------- persistent scan ----------
// 64 blocks, block g owns h columns [16g,16g+16). 4 waves, wave w = batches
// [16w,16w+16). Round 6 sync fabric: tagged data words, zero barriers in the
// main loop, waves fully decoupled (wave-plane w only depends on producer
// waves w of the other 63 blocks). ABA safe: double buffer + transitive
// certification (writing tag t+2 requires having consumed all of h_{t+1},
// which certifies every wave-plane consumed h_t).
__global__ __launch_bounds__(256, 1) void gru_scan(
    const unsigned short* __restrict__ xbf,
    const float* __restrict__ Wih,
    const float* __restrict__ mask,
    const float* __restrict__ init_h,
    const float* __restrict__ dmask,
    const float* __restrict__ Whh,
    const float* __restrict__ bih,
    const float* __restrict__ bhh,
    float* __restrict__ out,
    float* __restrict__ out_last,
    unsigned* __restrict__ hbuf32)       // 2 buffers of 64*1024 tagged words, zeroed
{
    __shared__ unsigned short wlds[48 * 1032];   // W_hh slice, rows r/z/n
    __shared__ unsigned short wxlds[48 * 520];   // W_ih slice

    const int g   = blockIdx.x;
    const int tid = threadIdx.x;
    const int w   = tid >> 6;
    const int l   = tid & 63;
    const int q   = l >> 4;          // k-quad
    const int c   = l & 15;          // n-col within block / m-row for A

    for (int idx = tid; idx < 48 * 1024; idx += 256) {
        int row = idx >> 10, col = idx & 1023;
        int sr = (row < 16) ? (g * 16 + row)
               : (row < 32) ? (H_ + g * 16 + row - 16)
                            : (2 * H_ + g * 16 + row - 32);
        wlds[row * 1032 + col] = f2bf(Whh[(size_t)sr * H_ + col]);
    }
    for (int idx = tid; idx < 48 * 512; idx += 256) {
        int row = idx >> 9, col = idx & 511;
        int sr = (row < 16) ? (g * 16 + row)
               : (row < 32) ? (H_ + g * 16 + row - 16)
                            : (2 * H_ + g * 16 + row - 32);
        wxlds[row * 520 + col] = f2bf(Wih[(size_t)sr * I_ + col]);
    }

    const int jd = g * 16 + c;
    const float b_r   = bih[jd] + bhh[jd];
    const float b_z   = bih[H_ + jd] + bhh[H_ + jd];
    const float bxn_b = bih[2 * H_ + jd];
    const float bhn_b = bhh[2 * H_ + jd];

    const int batch_A = w * 16 + c;

    float dm[4], hd[4], mc[4];
    int batch_C[4];
    #pragma unroll
    for (int r = 0; r < 4; ++r) {
        batch_C[r] = w * 16 + q * 4 + r;
        dm[r] = dmask[batch_C[r] * H_ + jd];
        float m1 = mask[batch_C[r] * S_ + 0];
        float h0 = init_h[batch_C[r] * H_ + jd];
        hd[r] = h0 * (dm[r] * m1 + 1.0f - m1);   // pre-dropped h for step 1
        mc[r] = m1;
        unsigned word = (1u << 16) | (unsigned)f2bf(hd[r]);   // tag = step 1
        __hip_atomic_store(&hbuf32[HWORDS + batch_C[r] * H_ + jd], word,
                           __ATOMIC_RELAXED, __HIP_MEMORY_SCOPE_AGENT);
    }
    __syncthreads();   // weights staged (the only barrier in this kernel)

    const int offx_r = c * 520,  offx_z = (16 + c) * 520,  offx_n = (32 + c) * 520;
    const unsigned short* wr = wlds + c * 1032 + q * 8;
    const unsigned short* wz = wlds + (16 + c) * 1032 + q * 8;
    const unsigned short* wn = wlds + (32 + c) * 1032 + q * 8;

    for (int t = 1; t <= S_; ++t) {
        const int s = t - 1;
        f32x4 ar, az, axn, ahn;
        #pragma unroll
        for (int r = 0; r < 4; ++r) { ar[r] = b_r; az[r] = b_z; axn[r] = bxn_b; ahn[r] = bhn_b; }

        float mn[4];
        if (t < S_) {
            #pragma unroll
            for (int r = 0; r < 4; ++r) mn[r] = mask[batch_C[r] * S_ + t];
        }

        // ---- x phase (h-independent; overlaps other blocks' h production,
        //      and our own tagged h-stores from step t-1 are in flight) ----
        {
            const unsigned short* xp = xbf + (size_t)batch_A * (S_ * I_) + s * I_ + q * 8;
            #pragma unroll 4
            for (int ki = 0; ki < 16; ++ki) {
                bf16x8 a  = ld8(xp + ki * 32);
                bf16x8 br = *(const bf16x8*)&wxlds[offx_r + q * 8 + ki * 32];
                bf16x8 bz = *(const bf16x8*)&wxlds[offx_z + q * 8 + ki * 32];
                bf16x8 bn = *(const bf16x8*)&wxlds[offx_n + q * 8 + ki * 32];
                ar  = __builtin_amdgcn_mfma_f32_16x16x32_bf16(a, br, ar, 0, 0, 0);
                az  = __builtin_amdgcn_mfma_f32_16x16x32_bf16(a, bz, az, 0, 0, 0);
                axn = __builtin_amdgcn_mfma_f32_16x16x32_bf16(a, bn, axn, 0, 0, 0);
            }
        }

        // ---- h phase: load-as-poll on tagged words, 4 pipelined groups ----
        {
            const unsigned* hb = hbuf32 + (size_t)(t & 1) * HWORDS + batch_A * H_ + q * 8;
            const unsigned tt = (unsigned)t << 16;
            u32x4 dA[16], dB[16];
            issue_group<0>(dA, hb);
            wait_group<0>(dA, hb, tt);       // absorbs nearly all waiting
            issue_group<1>(dB, hb);
            mfma_group<0>(dA, wr, wz, wn, ar, az, ahn);
            wait_group<1>(dB, hb, tt);
            issue_group<2>(dA, hb);
            mfma_group<1>(dB, wr, wz, wn, ar, az, ahn);
            wait_group<2>(dA, hb, tt);
            issue_group<3>(dB, hb);
            mfma_group<2>(dA, wr, wz, wn, ar, az, ahn);
            wait_group<3>(dB, hb, tt);
            mfma_group<3>(dB, wr, wz, wn, ar, az, ahn);
        }

        // ---- gates + state update ----
        #pragma unroll
        for (int r = 0; r < 4; ++r) {
            float rr = __builtin_amdgcn_rcpf(1.0f + __expf(-ar[r]));
            float zz = __builtin_amdgcn_rcpf(1.0f + __expf(-az[r]));
            float narg = axn[r] + rr * ahn[r];
            float E = __expf(-2.0f * fabsf(narg));
            float nn = copysignf((1.0f - E) * __builtin_amdgcn_rcpf(1.0f + E), narg);
            float m = mc[r];
            float curr = (1.0f - zz) * nn + zz * hd[r];
            float hnew = m * curr + (1.0f - m) * hd[r];
            out[((size_t)batch_C[r] * S_ + s) * H_ + jd] = hnew;
            if (t < S_) {
                hd[r] = hnew * (dm[r] * mn[r] + 1.0f - mn[r]);   // pre-drop for t+1
                mc[r] = mn[r];
                unsigned word = ((unsigned)(t + 1) << 16) | (unsigned)f2bf(hd[r]);
                __hip_atomic_store(&hbuf32[(size_t)((t + 1) & 1) * HWORDS
                                           + batch_C[r] * H_ + jd],
                                   word, __ATOMIC_RELAXED, __HIP_MEMORY_SCOPE_AGENT);
            } else {
                out_last[batch_C[r] * H_ + jd] = hnew;
            }
        }
        // pin the tagged stores here (don't let the compiler sink them past
        // the next iteration's x-phase — they're the other blocks' critical path)
        asm volatile("" ::: "memory");
    }
}

extern "C" void kernel_launch(void* const* d_in, const int* in_sizes, int n_in,
                              void* d_out, int out_size, void* d_ws, size_t ws_size,
                              hipStream_t stream) {
    (void)in_sizes; (void)n_in; (void)out_size; (void)ws_size;
    const float* x     = (const float*)d_in[0];
    const float* mask  = (const float*)d_in[1];
    const float* inith = (const float*)d_in[2];
    const float* dmask = (const float*)d_in[3];
    const float* Wih   = (const float*)d_in[4];
    const float* Whh   = (const float*)d_in[5];
    const float* bih   = (const float*)d_in[6];
    const float* bhh   = (const float*)d_in[7];
    float* out      = (float*)d_out;
    float* out_last = out + (size_t)B_ * S_ * H_;

    char* ws = (char*)d_ws;
    unsigned* hbuf32    = (unsigned*)ws;                     // 512 KB (2x tagged h)
    unsigned short* xbf = (unsigned short*)(ws + 524288);    // 32 MB

    hipMemsetAsync(ws, 0, 524288, stream);                   // tags <- 0
    gru_prep<<<2048, 256, 0, stream>>>(x, xbf);
    gru_scan<<<NB, 256, 0, stream>>>(xbf, Wih, mask, inith, dmask, Whh, bih, bhh,
                                     out, out_last, hbuf32);
}